// Round 1
// baseline (1154.731 us; speedup 1.0000x reference)
//
#include <hip/hip_runtime.h>
#include <math.h>

#define NTOK 8192
#define HD   2048
#define OD   1024
#define NE   8
#define CTXD 4096
#define CH   64

static const size_t OFF_VN = (size_t)NTOK * OD;                 // v_next
static const size_t OFF_RP = 2 * (size_t)NTOK * OD;             // router_probs
static const size_t OFF_TI = OFF_RP + (size_t)NTOK * NE;        // top_k_idx
static const size_t OFF_TP = OFF_TI + (size_t)NTOK * 2;         // top_k_probs

// ---------------- Router: logits -> softmax -> top2 -> renorm -> expert lists
__global__ __launch_bounds__(256) void router_kernel(
    const float* __restrict__ h,
    const float* __restrict__ rw,
    const float* __restrict__ rb,
    float* __restrict__ out,
    int* __restrict__ counts,
    int* __restrict__ list,
    float* __restrict__ wts)
{
    int lane = threadIdx.x & 63;
    int wv   = threadIdx.x >> 6;
    int b    = blockIdx.x * 4 + wv;
    const float* hrow = h + (size_t)b * HD;

    float a0=0.f,a1=0.f,a2=0.f,a3=0.f,a4=0.f,a5=0.f,a6=0.f,a7=0.f;
    for (int k = lane; k < HD; k += 64) {
        float hv = hrow[k];
        const float4* wr = (const float4*)(rw + (size_t)k * NE);
        float4 w0 = wr[0], w1 = wr[1];
        a0 = fmaf(hv, w0.x, a0); a1 = fmaf(hv, w0.y, a1);
        a2 = fmaf(hv, w0.z, a2); a3 = fmaf(hv, w0.w, a3);
        a4 = fmaf(hv, w1.x, a4); a5 = fmaf(hv, w1.y, a5);
        a6 = fmaf(hv, w1.z, a6); a7 = fmaf(hv, w1.w, a7);
    }
    #pragma unroll
    for (int off = 32; off >= 1; off >>= 1) {
        a0 += __shfl_xor(a0, off); a1 += __shfl_xor(a1, off);
        a2 += __shfl_xor(a2, off); a3 += __shfl_xor(a3, off);
        a4 += __shfl_xor(a4, off); a5 += __shfl_xor(a5, off);
        a6 += __shfl_xor(a6, off); a7 += __shfl_xor(a7, off);
    }
    if (lane == 0) {
        float lg[8] = {a0+rb[0], a1+rb[1], a2+rb[2], a3+rb[3],
                       a4+rb[4], a5+rb[5], a6+rb[6], a7+rb[7]};
        float m = lg[0];
        #pragma unroll
        for (int e2 = 1; e2 < 8; e2++) m = fmaxf(m, lg[e2]);
        float p[8]; float s = 0.f;
        #pragma unroll
        for (int e2 = 0; e2 < 8; e2++) { p[e2] = expf(lg[e2] - m); s += p[e2]; }
        float inv = 1.f / s;
        #pragma unroll
        for (int e2 = 0; e2 < 8; e2++) {
            p[e2] *= inv;
            out[OFF_RP + (size_t)b * 8 + e2] = p[e2];
        }
        // top-2, strict > so ties pick lowest index (jax top_k stable order)
        int e0 = 0;
        #pragma unroll
        for (int e2 = 1; e2 < 8; e2++) if (p[e2] > p[e0]) e0 = e2;
        int e1 = (e0 == 0) ? 1 : 0;
        #pragma unroll
        for (int e2 = 0; e2 < 8; e2++) {
            if (e2 == e0) continue;
            if (p[e2] > p[e1]) e1 = e2;
        }
        float s2 = p[e0] + p[e1];
        float w0 = p[e0] / s2;
        float w1 = p[e1] / s2;
        out[OFF_TI + (size_t)b*2 + 0] = (float)e0;
        out[OFF_TI + (size_t)b*2 + 1] = (float)e1;
        out[OFF_TP + (size_t)b*2 + 0] = w0;
        out[OFF_TP + (size_t)b*2 + 1] = w1;
        int p0 = atomicAdd(&counts[e0], 1);
        list[e0*NTOK + p0] = b; wts[e0*NTOK + p0] = w0;
        int p1 = atomicAdd(&counts[e1], 1);
        list[e1*NTOK + p1] = b; wts[e1*NTOK + p1] = w1;
    }
}

// ---------------- Expert-major controller + integrator + weighted scatter
__global__ __launch_bounds__(256) void expert_kernel(
    const float* __restrict__ h, const float* __restrict__ x,
    const float* __restrict__ v, const float* __restrict__ mu,
    const float* __restrict__ W1, const float* __restrict__ b1,
    const float* __restrict__ W2, const float* __restrict__ b2,
    const int* __restrict__ counts, const int* __restrict__ list,
    const float* __restrict__ wts,
    float* __restrict__ out)
{
    int e = blockIdx.y;
    int cnt = counts[e];
    int start = blockIdx.x * 32;
    if (start >= cnt) return;
    int nt = cnt - start; if (nt > 32) nt = 32;

    __shared__ float ctx[32][128];   // 16 KB, K-chunk of ctx
    __shared__ float hid[32][68];    // padded: stride 68 floats = 272B (16B aligned)
    __shared__ int   toks[32];
    __shared__ float twt[32];

    int tid = threadIdx.x;
    if (tid < 32) {
        int idx = (tid < nt) ? (start + tid) : start;
        toks[tid] = list[e*NTOK + idx];
        twt[tid]  = (tid < nt) ? wts[e*NTOK + idx] : 0.f;
    }
    __syncthreads();

    // ---- stage 1: hid[t][j] = relu(ctx[t,:] . W1[e][:,j] + b1[e][j])
    int j  = tid & 63;
    int tq = tid >> 6;           // 0..3, each handles 8 tokens
    float acc[8];
    #pragma unroll
    for (int i = 0; i < 8; i++) acc[i] = 0.f;
    const float* W1e = W1 + (size_t)e * CTXD * CH;

    for (int kc = 0; kc < CTXD; kc += 128) {
        #pragma unroll
        for (int i = 0; i < 4; i++) {
            int f4 = tid + i * 256;          // 1024 float4s = 32 tok x 32
            int t  = f4 >> 5;
            int c4 = (f4 & 31) * 4;
            int col = kc + c4;
            size_t tok = (size_t)toks[t];
            float4 val;
            if (col < HD)           val = *(const float4*)(h + tok*HD + col);
            else if (col < HD + OD) val = *(const float4*)(x + tok*OD + (col - HD));
            else                    val = *(const float4*)(v + tok*OD + (col - HD - OD));
            *(float4*)&ctx[t][c4] = val;
        }
        __syncthreads();
        for (int kk = 0; kk < 128; kk += 4) {
            int k = kc + kk;
            float w0 = W1e[(size_t)(k+0)*CH + j];
            float w1 = W1e[(size_t)(k+1)*CH + j];
            float w2 = W1e[(size_t)(k+2)*CH + j];
            float w3 = W1e[(size_t)(k+3)*CH + j];
            #pragma unroll
            for (int i = 0; i < 8; i++) {
                int t = tq*8 + i;
                float4 c = *(const float4*)&ctx[t][kk];
                acc[i] = fmaf(c.x, w0, acc[i]);
                acc[i] = fmaf(c.y, w1, acc[i]);
                acc[i] = fmaf(c.z, w2, acc[i]);
                acc[i] = fmaf(c.w, w3, acc[i]);
            }
        }
        __syncthreads();
    }
    {
        float bj = b1[e*CH + j];
        #pragma unroll
        for (int i = 0; i < 8; i++) {
            float hv = acc[i] + bj;
            hid[tq*8 + i][j] = hv > 0.f ? hv : 0.f;
        }
    }
    __syncthreads();

    // ---- stage 2: ctrl = hid @ W2[e] + b2[e]; fused integrator + scatter
    const float* W2e = W2 + (size_t)e * CH * 3 * OD;
    const float* b2e = b2 + (size_t)e * 3 * OD;
    int og = tid & 127;          // output column within 128-chunk
    int tg = tid >> 7;           // 0..1, each handles 16 tokens
    for (int oc = 0; oc < OD; oc += 128) {
        int o = oc + og;
        float aa[16], ab[16], ag[16];
        #pragma unroll
        for (int i = 0; i < 16; i++) { aa[i]=0.f; ab[i]=0.f; ag[i]=0.f; }
        for (int jc = 0; jc < CH; jc += 16) {
            float wa[16], wb[16], wg[16];
            #pragma unroll
            for (int jj = 0; jj < 16; jj++) {
                const float* r = W2e + (size_t)(jc + jj) * 3 * OD + o;
                wa[jj] = r[0];
                wb[jj] = r[OD];
                wg[jj] = r[2*OD];
            }
            #pragma unroll
            for (int i = 0; i < 16; i++) {
                int t = tg*16 + i;
                const float4* hp = (const float4*)&hid[t][jc];
                float4 h0 = hp[0], h1 = hp[1], h2 = hp[2], h3 = hp[3];
                float hv[16] = {h0.x,h0.y,h0.z,h0.w, h1.x,h1.y,h1.z,h1.w,
                                h2.x,h2.y,h2.z,h2.w, h3.x,h3.y,h3.z,h3.w};
                #pragma unroll
                for (int jj = 0; jj < 16; jj++) {
                    aa[i] = fmaf(hv[jj], wa[jj], aa[i]);
                    ab[i] = fmaf(hv[jj], wb[jj], ab[i]);
                    ag[i] = fmaf(hv[jj], wg[jj], ag[i]);
                }
            }
        }
        float b2a = b2e[o], b2b = b2e[OD + o], b2g = b2e[2*OD + o];
        float muo = mu[o];
        #pragma unroll
        for (int i = 0; i < 16; i++) {
            int t = tg*16 + i;
            if (t >= nt) continue;
            size_t tok = (size_t)toks[t];
            float w  = twt[t];
            float za = aa[i] + b2a;
            float zb = ab[i] + b2b;
            float zg = ag[i] + b2g;
            float alpha = 1.f / (1.f + expf(-za));
            float beta  = fmaxf(zb, 0.f) + log1pf(expf(-fabsf(zb)));  // softplus
            float gate  = 1.f / (1.f + expf(-zg));
            float xo = x[tok*OD + o];
            float vo = v[tok*OD + o];
            float vn = alpha * vo - beta * (xo - muo);
            float xn = xo + 0.1f * gate * vn;
            atomicAdd(&out[tok*OD + o],           w * xn);
            atomicAdd(&out[OFF_VN + tok*OD + o],  w * vn);
        }
    }
}

extern "C" void kernel_launch(void* const* d_in, const int* in_sizes, int n_in,
                              void* d_out, int out_size, void* d_ws, size_t ws_size,
                              hipStream_t stream)
{
    (void)in_sizes; (void)n_in; (void)out_size; (void)ws_size;
    const float* h  = (const float*)d_in[0];
    const float* x  = (const float*)d_in[1];
    const float* v  = (const float*)d_in[2];
    const float* rw = (const float*)d_in[3];
    const float* rb = (const float*)d_in[4];
    const float* mu = (const float*)d_in[5];
    const float* W1 = (const float*)d_in[6];
    const float* b1 = (const float*)d_in[7];
    const float* W2 = (const float*)d_in[8];
    const float* b2 = (const float*)d_in[9];
    float* out = (float*)d_out;

    int*   counts = (int*)d_ws;
    int*   list   = (int*)((char*)d_ws + 256);
    float* wts    = (float*)((char*)d_ws + 256 + (size_t)NE*NTOK*4);

    // zero x_next/v_next (atomic accumulation targets) and expert counts
    hipMemsetAsync(d_out, 0, 2 * (size_t)NTOK * OD * sizeof(float), stream);
    hipMemsetAsync(counts, 0, NE * sizeof(int), stream);

    router_kernel<<<NTOK/4, 256, 0, stream>>>(h, rw, rb, out, counts, list, wts);

    dim3 grid(NTOK/32, NE);
    expert_kernel<<<grid, 256, 0, stream>>>(h, x, v, mu, W1, b1, W2, b2,
                                            counts, list, wts, out);
}

// Round 2
// 312.619 us; speedup vs baseline: 3.6937x; 3.6937x over previous
//
#include <hip/hip_runtime.h>
#include <math.h>

#define NTOK 8192
#define HD   2048
#define OD   1024
#define NE   8
#define CTXD 4096
#define CH   64

typedef short bf16x8 __attribute__((ext_vector_type(8)));
typedef float f32x4  __attribute__((ext_vector_type(4)));

static const size_t OFF_VN = (size_t)NTOK * OD;                 // v_next
static const size_t OFF_RP = 2 * (size_t)NTOK * OD;             // router_probs
static const size_t OFF_TI = OFF_RP + (size_t)NTOK * NE;        // top_k_idx
static const size_t OFF_TP = OFF_TI + (size_t)NTOK * 2;         // top_k_probs

// ---- ws byte offsets ----
#define WS_PCNT   0                                  // 64 ints
#define WS_TOTAL  256                                // 1 int
#define WS_TABLE  512                                // <=512 ints
#define WS_PLIST  4096                               // 64*8192 ints   (2 MB)
#define WS_PWTS   (4096 + 64*NTOK*4)                 // 64*8192 float2 (4 MB)
#define WS_W1P    (WS_PWTS + 64*NTOK*8)              // 8*4096*64 bf16 (4 MB)
#define WS_W2P    (WS_W1P + NE*CTXD*CH*2)            // 8*64*3072 bf16 (3 MB)

__device__ __forceinline__ unsigned bfpack2(float a, float b) {
    unsigned ua = __float_as_uint(a), ub = __float_as_uint(b);
    ua = (ua + 0x7FFFu + ((ua >> 16) & 1u)) >> 16;
    ub = (ub + 0x7FFFu + ((ub >> 16) & 1u)) >> 16;
    return ua | (ub << 16);
}
__device__ __forceinline__ unsigned short bf1(float a) {
    unsigned ua = __float_as_uint(a);
    return (unsigned short)((ua + 0x7FFFu + ((ua >> 16) & 1u)) >> 16);
}

// ---------------- weight pre-convert: W1 [8][4096][64] -> W1p [8][512][64][8] bf16
__global__ __launch_bounds__(256) void convert_w1(const float* __restrict__ W1,
                                                  unsigned short* __restrict__ W1p) {
    int flat = blockIdx.x * 256 + threadIdx.x;          // 8*512*64 = 262144
    int e = flat >> 15, rem = flat & 32767;
    int kb = rem >> 6, c = rem & 63;
    const float* src = W1 + (size_t)e * CTXD * CH + (size_t)kb * 8 * CH + c;
    uint4 o;
    o.x = bfpack2(src[0 * 64], src[1 * 64]);
    o.y = bfpack2(src[2 * 64], src[3 * 64]);
    o.z = bfpack2(src[4 * 64], src[5 * 64]);
    o.w = bfpack2(src[6 * 64], src[7 * 64]);
    *(uint4*)(W1p + (size_t)flat * 8) = o;
}

// W2 [8][64][3072] -> W2p [8][8][3072][8] bf16
__global__ __launch_bounds__(256) void convert_w2(const float* __restrict__ W2,
                                                  unsigned short* __restrict__ W2p) {
    int flat = blockIdx.x * 256 + threadIdx.x;          // 8*8*3072 = 196608
    int e = flat / 24576, rem = flat - e * 24576;
    int kb = rem / 3072, c = rem - kb * 3072;
    const float* src = W2 + ((size_t)e * CH + kb * 8) * (3 * OD) + c;
    uint4 o;
    o.x = bfpack2(src[0 * 3072], src[1 * 3072]);
    o.y = bfpack2(src[2 * 3072], src[3 * 3072]);
    o.z = bfpack2(src[4 * 3072], src[5 * 3072]);
    o.w = bfpack2(src[6 * 3072], src[7 * 3072]);
    *(uint4*)(W2p + (size_t)flat * 8) = o;
}

// ---------------- Router: softmax -> top2 -> renorm -> pair-group lists
__global__ __launch_bounds__(256) void router_kernel(
    const float* __restrict__ h, const float* __restrict__ rw,
    const float* __restrict__ rb, float* __restrict__ out,
    int* __restrict__ pcnt, int* __restrict__ plist, float2* __restrict__ pwts)
{
    int lane = threadIdx.x & 63;
    int wv   = threadIdx.x >> 6;
    int b    = blockIdx.x * 4 + wv;
    const float4* h4 = (const float4*)(h + (size_t)b * HD);

    float a0=0.f,a1=0.f,a2=0.f,a3=0.f,a4=0.f,a5=0.f,a6=0.f,a7=0.f;
    #pragma unroll
    for (int i = 0; i < 8; i++) {
        int k4 = i * 64 + lane;                          // float4 index, k = 4*k4
        float4 hv = h4[k4];
        const float4* wr = (const float4*)rw + (size_t)k4 * 8;  // rows 4k4..4k4+3
        float4 w00 = wr[0], w01 = wr[1];
        float4 w10 = wr[2], w11 = wr[3];
        float4 w20 = wr[4], w21 = wr[5];
        float4 w30 = wr[6], w31 = wr[7];
        a0 = fmaf(hv.x,w00.x,fmaf(hv.y,w10.x,fmaf(hv.z,w20.x,fmaf(hv.w,w30.x,a0))));
        a1 = fmaf(hv.x,w00.y,fmaf(hv.y,w10.y,fmaf(hv.z,w20.y,fmaf(hv.w,w30.y,a1))));
        a2 = fmaf(hv.x,w00.z,fmaf(hv.y,w10.z,fmaf(hv.z,w20.z,fmaf(hv.w,w30.z,a2))));
        a3 = fmaf(hv.x,w00.w,fmaf(hv.y,w10.w,fmaf(hv.z,w20.w,fmaf(hv.w,w30.w,a3))));
        a4 = fmaf(hv.x,w01.x,fmaf(hv.y,w11.x,fmaf(hv.z,w21.x,fmaf(hv.w,w31.x,a4))));
        a5 = fmaf(hv.x,w01.y,fmaf(hv.y,w11.y,fmaf(hv.z,w21.y,fmaf(hv.w,w31.y,a5))));
        a6 = fmaf(hv.x,w01.z,fmaf(hv.y,w11.z,fmaf(hv.z,w21.z,fmaf(hv.w,w31.z,a6))));
        a7 = fmaf(hv.x,w01.w,fmaf(hv.y,w11.w,fmaf(hv.z,w21.w,fmaf(hv.w,w31.w,a7))));
    }
    #pragma unroll
    for (int off = 32; off >= 1; off >>= 1) {
        a0 += __shfl_xor(a0, off); a1 += __shfl_xor(a1, off);
        a2 += __shfl_xor(a2, off); a3 += __shfl_xor(a3, off);
        a4 += __shfl_xor(a4, off); a5 += __shfl_xor(a5, off);
        a6 += __shfl_xor(a6, off); a7 += __shfl_xor(a7, off);
    }
    if (lane == 0) {
        float lg[8] = {a0+rb[0], a1+rb[1], a2+rb[2], a3+rb[3],
                       a4+rb[4], a5+rb[5], a6+rb[6], a7+rb[7]};
        float m = lg[0];
        #pragma unroll
        for (int e2 = 1; e2 < 8; e2++) m = fmaxf(m, lg[e2]);
        float p[8]; float s = 0.f;
        #pragma unroll
        for (int e2 = 0; e2 < 8; e2++) { p[e2] = expf(lg[e2] - m); s += p[e2]; }
        float inv = 1.f / s;
        #pragma unroll
        for (int e2 = 0; e2 < 8; e2++) {
            p[e2] *= inv;
            out[OFF_RP + (size_t)b * 8 + e2] = p[e2];
        }
        int e0 = 0;
        #pragma unroll
        for (int e2 = 1; e2 < 8; e2++) if (p[e2] > p[e0]) e0 = e2;
        int e1 = (e0 == 0) ? 1 : 0;
        #pragma unroll
        for (int e2 = 0; e2 < 8; e2++) {
            if (e2 == e0) continue;
            if (p[e2] > p[e1]) e1 = e2;
        }
        float s2 = p[e0] + p[e1];
        float w0 = p[e0] / s2, w1 = p[e1] / s2;
        out[OFF_TI + (size_t)b*2 + 0] = (float)e0;
        out[OFF_TI + (size_t)b*2 + 1] = (float)e1;
        out[OFF_TP + (size_t)b*2 + 0] = w0;
        out[OFF_TP + (size_t)b*2 + 1] = w1;
        int lo = min(e0, e1), hi = max(e0, e1);
        float wlo = (e0 < e1) ? w0 : w1;
        float whi = (e0 < e1) ? w1 : w0;
        int pid = lo * 8 + hi;
        int pos = atomicAdd(&pcnt[pid], 1);
        plist[pid * NTOK + pos] = b;
        pwts[pid * NTOK + pos] = make_float2(wlo, whi);
    }
}

// ---------------- prefix: pid counts -> dense tile table
__global__ void prefix_kernel(const int* __restrict__ pcnt,
                              int* __restrict__ table, int* __restrict__ total) {
    int tid = threadIdx.x;                  // 64 threads, 1 wave
    int cnt = pcnt[tid];
    int tiles = (cnt + 31) >> 5;
    int incl = tiles;
    #pragma unroll
    for (int off = 1; off < 64; off <<= 1) {
        int v = __shfl_up(incl, off);
        if (tid >= off) incl += v;
    }
    int base = incl - tiles;
    for (int i = 0; i < tiles; i++) table[base + i] = tid | (i << 6);
    if (tid == 63) *total = incl;
}

// ---------------- fused MoE: GEMM1(bf16 MFMA) -> GEMM2 -> integrator -> store
__global__ __launch_bounds__(512) void moe_kernel(
    const float* __restrict__ h, const float* __restrict__ x,
    const float* __restrict__ v, const float* __restrict__ mu,
    const float* __restrict__ b1, const float* __restrict__ b2,
    const unsigned short* __restrict__ W1p, const unsigned short* __restrict__ W2p,
    const int* __restrict__ pcnt, const int* __restrict__ table,
    const int* __restrict__ total, const int* __restrict__ plist,
    const float2* __restrict__ pwts, float* __restrict__ out)
{
    __shared__ unsigned short ctx_s[32 * 128];   // swizzled bf16 tile [32 tok][128 k]
    __shared__ unsigned short hid_s[32 * 128];   // swizzled bf16 [32 tok][128 = 2*64 hid]
    __shared__ int    toks[32];
    __shared__ float2 tw[32];

    int bid = blockIdx.x;
    if (bid >= *total) return;
    int entry = table[bid];
    int pid = entry & 63;
    int start = (entry >> 6) * 32;
    int lo = pid >> 3, hi = pid & 7;
    int cnt = pcnt[pid];
    int nt = cnt - start; if (nt > 32) nt = 32;

    int tid = threadIdx.x;
    if (tid < 32) {
        int idx = start + (tid < nt ? tid : 0);
        toks[tid] = plist[pid * NTOK + idx];
        tw[tid]   = pwts[pid * NTOK + idx];
    }
    __syncthreads();

    int lane = tid & 63, w = tid >> 6;           // 8 waves
    int l15 = lane & 15, lq = lane >> 4;         // lq = 0..3
    int myE  = (w < 4) ? lo : hi;
    int colw = (w & 3) * 16 + l15;               // col within expert's 64
    const unsigned short* W1e = W1p + (size_t)myE * (CTXD * CH);

    // staging map: 512 thr x 8 floats = 32 tok x 128 k
    int st_t = tid >> 4, st_seg = tid & 15;
    int tok_st = toks[st_t];
    const float* hb = h + (size_t)tok_st * HD;
    const float* xb = x + (size_t)tok_st * OD;
    const float* vb = v + (size_t)tok_st * OD;
    int st_byte = (st_t * 256 + st_seg * 16) ^ ((st_t & 7) << 4);

    f32x4 acc0 = {0.f,0.f,0.f,0.f}, acc1 = {0.f,0.f,0.f,0.f};

    for (int kc = 0; kc < CTXD; kc += 128) {
        int kq = kc + st_seg * 8;
        const float* src;
        if (kq < HD)            src = hb + kq;
        else if (kq < HD + OD)  src = xb + (kq - HD);
        else                    src = vb + (kq - HD - OD);
        float4 f0 = ((const float4*)src)[0];
        float4 f1 = ((const float4*)src)[1];
        uint4 pk;
        pk.x = bfpack2(f0.x, f0.y); pk.y = bfpack2(f0.z, f0.w);
        pk.z = bfpack2(f1.x, f1.y); pk.w = bfpack2(f1.z, f1.w);
        *(uint4*)((char*)ctx_s + st_byte) = pk;
        __syncthreads();

        #pragma unroll
        for (int ks = 0; ks < 4; ks++) {
            int k0 = ks * 32 + lq * 8;                       // k within chunk
            int rb0 = ((l15      ) * 256 + k0 * 2) ^ ((l15 & 7) << 4);
            int rb1 = ((l15 + 16 ) * 256 + k0 * 2) ^ ((l15 & 7) << 4);
            bf16x8 a0 = *(const bf16x8*)((char*)ctx_s + rb0);
            bf16x8 a1 = *(const bf16x8*)((char*)ctx_s + rb1);
            int kglob = kc + k0;
            bf16x8 bfr = *(const bf16x8*)(W1e + ((size_t)(kglob >> 3) * 64 + colw) * 8);
            acc0 = __builtin_amdgcn_mfma_f32_16x16x32_bf16(a0, bfr, acc0, 0, 0, 0);
            acc1 = __builtin_amdgcn_mfma_f32_16x16x32_bf16(a1, bfr, acc1, 0, 0, 0);
        }
        __syncthreads();
    }

    // relu + bias -> hid LDS (bf16, swizzled). acc row = lq*4+i, col = colw (per expert)
    {
        float b1v = b1[myE * CH + colw];
        int colh = ((w >= 4) ? 64 : 0) + colw;
        #pragma unroll
        for (int i = 0; i < 4; i++) {
            int r0 = lq * 4 + i;
            float h0 = acc0[i] + b1v; h0 = h0 > 0.f ? h0 : 0.f;
            float h1 = acc1[i] + b1v; h1 = h1 > 0.f ? h1 : 0.f;
            int by0 = (r0 * 256 + colh * 2) ^ ((r0 & 7) << 4);
            int by1 = ((r0 + 16) * 256 + colh * 2) ^ ((r0 & 7) << 4);
            *(unsigned short*)((char*)hid_s + by0) = bf1(h0);
            *(unsigned short*)((char*)hid_s + by1) = bf1(h1);
        }
    }
    __syncthreads();

    // ---- stage 2: per o-tile, 2 experts x {alpha,beta,gate} tiles, fused integrator
    bf16x8 af[2][2][2];                          // [slot][ks][rowtile]
    #pragma unroll
    for (int s = 0; s < 2; s++)
        #pragma unroll
        for (int ks = 0; ks < 2; ks++)
            #pragma unroll
            for (int rt = 0; rt < 2; rt++) {
                int row = rt * 16 + l15;
                int col = s * 64 + ks * 32 + lq * 8;
                int by = (row * 256 + col * 2) ^ ((row & 7) << 4);
                af[s][ks][rt] = *(const bf16x8*)((char*)hid_s + by);
            }
    const unsigned short* W2lo = W2p + (size_t)lo * (CH * 3 * OD);
    const unsigned short* W2hi = W2p + (size_t)hi * (CH * 3 * OD);

    for (int ot = w; ot < 64; ot += 8) {
        int o = ot * 16 + l15;
        f32x4 acc[2][3][2];
        #pragma unroll
        for (int s = 0; s < 2; s++)
            #pragma unroll
            for (int q = 0; q < 3; q++)
                #pragma unroll
                for (int rt = 0; rt < 2; rt++) acc[s][q][rt] = (f32x4){0.f,0.f,0.f,0.f};
        #pragma unroll
        for (int s = 0; s < 2; s++) {
            const unsigned short* W2e = s ? W2hi : W2lo;
            #pragma unroll
            for (int q = 0; q < 3; q++) {
                int c = q * OD + o;
                #pragma unroll
                for (int ks = 0; ks < 2; ks++) {
                    int kb = ks * 4 + lq;
                    bf16x8 bfr = *(const bf16x8*)(W2e + ((size_t)kb * 3072 + c) * 8);
                    acc[s][q][0] = __builtin_amdgcn_mfma_f32_16x16x32_bf16(af[s][ks][0], bfr, acc[s][q][0], 0, 0, 0);
                    acc[s][q][1] = __builtin_amdgcn_mfma_f32_16x16x32_bf16(af[s][ks][1], bfr, acc[s][q][1], 0, 0, 0);
                }
            }
        }
        float ba_lo = b2[(size_t)lo*3072 + o],  bb_lo = b2[(size_t)lo*3072 + OD + o],  bg_lo = b2[(size_t)lo*3072 + 2*OD + o];
        float ba_hi = b2[(size_t)hi*3072 + o],  bb_hi = b2[(size_t)hi*3072 + OD + o],  bg_hi = b2[(size_t)hi*3072 + 2*OD + o];
        float muo = mu[o];
        #pragma unroll
        for (int rt = 0; rt < 2; rt++) {
            #pragma unroll
            for (int i = 0; i < 4; i++) {
                int trow = rt * 16 + lq * 4 + i;
                if (trow >= nt) continue;
                int tok = toks[trow];
                float2 tww = tw[trow];
                float xo = x[(size_t)tok * OD + o];
                float vo = v[(size_t)tok * OD + o];
                float err = xo - muo;
                // expert lo
                float za = acc[0][0][rt][i] + ba_lo;
                float zb = acc[0][1][rt][i] + bb_lo;
                float zg = acc[0][2][rt][i] + bg_lo;
                float al0 = 1.f / (1.f + expf(-za));
                float be0 = fmaxf(zb, 0.f) + log1pf(expf(-fabsf(zb)));
                float ga0 = 1.f / (1.f + expf(-zg));
                float vn0 = al0 * vo - be0 * err;
                // expert hi
                za = acc[1][0][rt][i] + ba_hi;
                zb = acc[1][1][rt][i] + bb_hi;
                zg = acc[1][2][rt][i] + bg_hi;
                float al1 = 1.f / (1.f + expf(-za));
                float be1 = fmaxf(zb, 0.f) + log1pf(expf(-fabsf(zb)));
                float ga1 = 1.f / (1.f + expf(-zg));
                float vn1 = al1 * vo - be1 * err;

                float vn = tww.x * vn0 + tww.y * vn1;
                float xn = xo + 0.1f * (tww.x * ga0 * vn0 + tww.y * ga1 * vn1);
                out[(size_t)tok * OD + o]          = xn;
                out[OFF_VN + (size_t)tok * OD + o] = vn;
            }
        }
    }
}

extern "C" void kernel_launch(void* const* d_in, const int* in_sizes, int n_in,
                              void* d_out, int out_size, void* d_ws, size_t ws_size,
                              hipStream_t stream)
{
    (void)in_sizes; (void)n_in; (void)out_size; (void)ws_size;
    const float* h  = (const float*)d_in[0];
    const float* x  = (const float*)d_in[1];
    const float* v  = (const float*)d_in[2];
    const float* rw = (const float*)d_in[3];
    const float* rb = (const float*)d_in[4];
    const float* mu = (const float*)d_in[5];
    const float* W1 = (const float*)d_in[6];
    const float* b1 = (const float*)d_in[7];
    const float* W2 = (const float*)d_in[8];
    const float* b2 = (const float*)d_in[9];
    float* out = (float*)d_out;

    char* ws = (char*)d_ws;
    int*    pcnt  = (int*)(ws + WS_PCNT);
    int*    total = (int*)(ws + WS_TOTAL);
    int*    table = (int*)(ws + WS_TABLE);
    int*    plist = (int*)(ws + WS_PLIST);
    float2* pwts  = (float2*)(ws + WS_PWTS);
    unsigned short* W1p = (unsigned short*)(ws + WS_W1P);
    unsigned short* W2p = (unsigned short*)(ws + WS_W2P);

    hipMemsetAsync(pcnt, 0, 64 * sizeof(int), stream);

    convert_w1<<<1024, 256, 0, stream>>>(W1, W1p);
    convert_w2<<<768, 256, 0, stream>>>(W2, W2p);
    router_kernel<<<NTOK / 4, 256, 0, stream>>>(h, rw, rb, out, pcnt, plist, pwts);
    prefix_kernel<<<1, 64, 0, stream>>>(pcnt, table, total);
    moe_kernel<<<320, 512, 0, stream>>>(h, x, v, mu, b1, b2, W1p, W2p,
                                        pcnt, table, total, plist, pwts, out);
}

// Round 3
// 225.231 us; speedup vs baseline: 5.1269x; 1.3880x over previous
//
#include <hip/hip_runtime.h>
#include <math.h>

#define NTOK 8192
#define HD   2048
#define OD   1024
#define NE   8
#define CTXD 4096
#define CH   64

typedef short bf16x8 __attribute__((ext_vector_type(8)));
typedef float f32x4  __attribute__((ext_vector_type(4)));

static const size_t OFF_VN = (size_t)NTOK * OD;                 // v_next
static const size_t OFF_RP = 2 * (size_t)NTOK * OD;             // router_probs
static const size_t OFF_TI = OFF_RP + (size_t)NTOK * NE;        // top_k_idx
static const size_t OFF_TP = OFF_TI + (size_t)NTOK * 2;         // top_k_probs

// ---- ws byte offsets ----
#define WS_PCNT   0                                  // 64 ints
#define WS_TOTAL  256                                // 1 int
#define WS_TABLE  512                                // <=896 ints
#define WS_PLIST  4096                               // 64*8192 ints   (2 MB)
#define WS_PWTS   (4096 + 64*NTOK*4)                 // 64*8192 float2 (4 MB)
#define WS_W1P    (WS_PWTS + 64*NTOK*8)              // 8*4096*64 bf16 (4 MB)
#define WS_W2P    (WS_W1P + NE*CTXD*CH*2)            // 8*64*3072 bf16 (3 MB)

__device__ __forceinline__ unsigned bfpack2(float a, float b) {
    unsigned ua = __float_as_uint(a), ub = __float_as_uint(b);
    ua = (ua + 0x7FFFu + ((ua >> 16) & 1u)) >> 16;
    ub = (ub + 0x7FFFu + ((ub >> 16) & 1u)) >> 16;
    return ua | (ub << 16);
}
__device__ __forceinline__ unsigned short bf1(float a) {
    unsigned ua = __float_as_uint(a);
    return (unsigned short)((ua + 0x7FFFu + ((ua >> 16) & 1u)) >> 16);
}
__device__ __forceinline__ float fsigmoid(float z) {
    return __fdividef(1.f, 1.f + __expf(-z));
}
__device__ __forceinline__ float fsoftplus(float z) {
    return fmaxf(z, 0.f) + __logf(1.f + __expf(-fabsf(z)));
}

// ---------------- weight pre-convert: W1 [8][4096][64] -> W1p [8][512][64][8] bf16
__global__ __launch_bounds__(256) void convert_w1(const float* __restrict__ W1,
                                                  unsigned short* __restrict__ W1p) {
    int flat = blockIdx.x * 256 + threadIdx.x;          // 8*512*64 = 262144
    int e = flat >> 15, rem = flat & 32767;
    int kb = rem >> 6, c = rem & 63;
    const float* src = W1 + (size_t)e * CTXD * CH + (size_t)kb * 8 * CH + c;
    uint4 o;
    o.x = bfpack2(src[0 * 64], src[1 * 64]);
    o.y = bfpack2(src[2 * 64], src[3 * 64]);
    o.z = bfpack2(src[4 * 64], src[5 * 64]);
    o.w = bfpack2(src[6 * 64], src[7 * 64]);
    *(uint4*)(W1p + (size_t)flat * 8) = o;
}

// W2 [8][64][3072] -> W2p [8][8][3072][8] bf16
__global__ __launch_bounds__(256) void convert_w2(const float* __restrict__ W2,
                                                  unsigned short* __restrict__ W2p) {
    int flat = blockIdx.x * 256 + threadIdx.x;          // 8*8*3072 = 196608
    int e = flat / 24576, rem = flat - e * 24576;
    int kb = rem / 3072, c = rem - kb * 3072;
    const float* src = W2 + ((size_t)e * CH + kb * 8) * (3 * OD) + c;
    uint4 o;
    o.x = bfpack2(src[0 * 3072], src[1 * 3072]);
    o.y = bfpack2(src[2 * 3072], src[3 * 3072]);
    o.z = bfpack2(src[4 * 3072], src[5 * 3072]);
    o.w = bfpack2(src[6 * 3072], src[7 * 3072]);
    *(uint4*)(W2p + (size_t)flat * 8) = o;
}

// ---------------- Router: softmax -> top2 -> renorm -> pair-group lists
__global__ __launch_bounds__(256) void router_kernel(
    const float* __restrict__ h, const float* __restrict__ rw,
    const float* __restrict__ rb, float* __restrict__ out,
    int* __restrict__ pcnt, int* __restrict__ plist, float2* __restrict__ pwts)
{
    int lane = threadIdx.x & 63;
    int wv   = threadIdx.x >> 6;
    int b    = blockIdx.x * 4 + wv;
    const float4* h4 = (const float4*)(h + (size_t)b * HD);

    float a0=0.f,a1=0.f,a2=0.f,a3=0.f,a4=0.f,a5=0.f,a6=0.f,a7=0.f;
    #pragma unroll
    for (int i = 0; i < 8; i++) {
        int k4 = i * 64 + lane;                          // float4 index, k = 4*k4
        float4 hv = h4[k4];
        const float4* wr = (const float4*)rw + (size_t)k4 * 8;  // rows 4k4..4k4+3
        float4 w00 = wr[0], w01 = wr[1];
        float4 w10 = wr[2], w11 = wr[3];
        float4 w20 = wr[4], w21 = wr[5];
        float4 w30 = wr[6], w31 = wr[7];
        a0 = fmaf(hv.x,w00.x,fmaf(hv.y,w10.x,fmaf(hv.z,w20.x,fmaf(hv.w,w30.x,a0))));
        a1 = fmaf(hv.x,w00.y,fmaf(hv.y,w10.y,fmaf(hv.z,w20.y,fmaf(hv.w,w30.y,a1))));
        a2 = fmaf(hv.x,w00.z,fmaf(hv.y,w10.z,fmaf(hv.z,w20.z,fmaf(hv.w,w30.z,a2))));
        a3 = fmaf(hv.x,w00.w,fmaf(hv.y,w10.w,fmaf(hv.z,w20.w,fmaf(hv.w,w30.w,a3))));
        a4 = fmaf(hv.x,w01.x,fmaf(hv.y,w11.x,fmaf(hv.z,w21.x,fmaf(hv.w,w31.x,a4))));
        a5 = fmaf(hv.x,w01.y,fmaf(hv.y,w11.y,fmaf(hv.z,w21.y,fmaf(hv.w,w31.y,a5))));
        a6 = fmaf(hv.x,w01.z,fmaf(hv.y,w11.z,fmaf(hv.z,w21.z,fmaf(hv.w,w31.z,a6))));
        a7 = fmaf(hv.x,w01.w,fmaf(hv.y,w11.w,fmaf(hv.z,w21.w,fmaf(hv.w,w31.w,a7))));
    }
    #pragma unroll
    for (int off = 32; off >= 1; off >>= 1) {
        a0 += __shfl_xor(a0, off); a1 += __shfl_xor(a1, off);
        a2 += __shfl_xor(a2, off); a3 += __shfl_xor(a3, off);
        a4 += __shfl_xor(a4, off); a5 += __shfl_xor(a5, off);
        a6 += __shfl_xor(a6, off); a7 += __shfl_xor(a7, off);
    }
    if (lane == 0) {
        float lg[8] = {a0+rb[0], a1+rb[1], a2+rb[2], a3+rb[3],
                       a4+rb[4], a5+rb[5], a6+rb[6], a7+rb[7]};
        float m = lg[0];
        #pragma unroll
        for (int e2 = 1; e2 < 8; e2++) m = fmaxf(m, lg[e2]);
        float p[8]; float s = 0.f;
        #pragma unroll
        for (int e2 = 0; e2 < 8; e2++) { p[e2] = expf(lg[e2] - m); s += p[e2]; }
        float inv = 1.f / s;
        #pragma unroll
        for (int e2 = 0; e2 < 8; e2++) {
            p[e2] *= inv;
            out[OFF_RP + (size_t)b * 8 + e2] = p[e2];
        }
        int e0 = 0;
        #pragma unroll
        for (int e2 = 1; e2 < 8; e2++) if (p[e2] > p[e0]) e0 = e2;
        int e1 = (e0 == 0) ? 1 : 0;
        #pragma unroll
        for (int e2 = 0; e2 < 8; e2++) {
            if (e2 == e0) continue;
            if (p[e2] > p[e1]) e1 = e2;
        }
        float s2 = p[e0] + p[e1];
        float w0 = p[e0] / s2, w1 = p[e1] / s2;
        out[OFF_TI + (size_t)b*2 + 0] = (float)e0;
        out[OFF_TI + (size_t)b*2 + 1] = (float)e1;
        out[OFF_TP + (size_t)b*2 + 0] = w0;
        out[OFF_TP + (size_t)b*2 + 1] = w1;
        int lo = min(e0, e1), hi = max(e0, e1);
        float wlo = (e0 < e1) ? w0 : w1;
        float whi = (e0 < e1) ? w1 : w0;
        int pid = lo * 8 + hi;
        int pos = atomicAdd(&pcnt[pid], 1);
        plist[pid * NTOK + pos] = b;
        pwts[pid * NTOK + pos] = make_float2(wlo, whi);
    }
}

// ---------------- prefix: pid counts -> dense tile table
__global__ void prefix_kernel(const int* __restrict__ pcnt,
                              int* __restrict__ table, int* __restrict__ total) {
    int tid = threadIdx.x;                  // 64 threads, 1 wave
    int cnt = pcnt[tid];
    int tiles = (cnt + 31) >> 5;
    int incl = tiles;
    #pragma unroll
    for (int off = 1; off < 64; off <<= 1) {
        int v = __shfl_up(incl, off);
        if (tid >= off) incl += v;
    }
    int base = incl - tiles;
    for (int i = 0; i < tiles; i++) table[base + i] = tid | (i << 6);
    if (tid == 63) *total = incl;
}

// ---------------- fused MoE: pipelined GEMM1 -> GEMM2 -> integrator -> store
__global__ __launch_bounds__(512) void moe_kernel(
    const float* __restrict__ h, const float* __restrict__ x,
    const float* __restrict__ v, const float* __restrict__ mu,
    const float* __restrict__ b1, const float* __restrict__ b2,
    const unsigned short* __restrict__ W1p, const unsigned short* __restrict__ W2p,
    const int* __restrict__ pcnt, const int* __restrict__ table,
    const int* __restrict__ total, const int* __restrict__ plist,
    const float2* __restrict__ pwts, float* __restrict__ out)
{
    __shared__ unsigned short ctx_s[2][32 * 128];  // dbuf swizzled bf16 [32 tok][128 k]
    __shared__ unsigned short hid_s[32 * 128];     // swizzled bf16 [32 tok][128 = 2*64]
    __shared__ int    toks[32];
    __shared__ float2 tw[32];

    int bid = blockIdx.x;
    if (bid >= *total) return;
    int entry = table[bid];
    int pid = entry & 63;
    int start = (entry >> 6) * 32;
    int lo = pid >> 3, hi = pid & 7;
    int cnt = pcnt[pid];
    int nt = cnt - start; if (nt > 32) nt = 32;

    int tid = threadIdx.x;
    if (tid < 32) {
        int idx = start + (tid < nt ? tid : 0);
        toks[tid] = plist[pid * NTOK + idx];
        tw[tid]   = pwts[pid * NTOK + idx];
    }
    __syncthreads();

    int lane = tid & 63, w = tid >> 6;           // 8 waves
    int l15 = lane & 15, lq = lane >> 4;         // lq = 0..3
    int myE  = (w < 4) ? lo : hi;
    int colw = (w & 3) * 16 + l15;               // col within expert's 64
    const unsigned short* W1e = W1p + (size_t)myE * (CTXD * CH);

    // staging map: 512 thr x 8 floats = 32 tok x 128 k
    int st_t = tid >> 4, st_seg = tid & 15;
    int tok_st = toks[st_t];
    const float* hb = h + (size_t)tok_st * HD;
    const float* xb = x + (size_t)tok_st * OD;
    const float* vb = v + (size_t)tok_st * OD;
    int st_byte = (st_t * 256 + st_seg * 16) ^ ((st_t & 7) << 4);

#define LOADC(KC, C0, C1) do {                                               \
        int kq = (KC) * 128 + st_seg * 8;                                    \
        const float* _s;                                                     \
        if (kq < HD)            _s = hb + kq;                                \
        else if (kq < HD + OD)  _s = xb + (kq - HD);                         \
        else                    _s = vb + (kq - HD - OD);                    \
        C0 = ((const float4*)_s)[0];                                         \
        C1 = ((const float4*)_s)[1];                                         \
    } while (0)

#define PACKW(C0, C1, BUF) do {                                              \
        uint4 pk;                                                            \
        pk.x = bfpack2(C0.x, C0.y); pk.y = bfpack2(C0.z, C0.w);              \
        pk.z = bfpack2(C1.x, C1.y); pk.w = bfpack2(C1.z, C1.w);              \
        *(uint4*)((char*)(ctx_s[BUF]) + st_byte) = pk;                       \
    } while (0)

#define MFMAC(KC, BUF) do {                                                  \
        _Pragma("unroll")                                                    \
        for (int ks = 0; ks < 4; ks++) {                                     \
            int k0 = ks * 32 + lq * 8;                                       \
            int rb0 = ((l15     ) * 256 + k0 * 2) ^ ((l15 & 7) << 4);        \
            int rb1 = ((l15 + 16) * 256 + k0 * 2) ^ ((l15 & 7) << 4);        \
            bf16x8 a0 = *(const bf16x8*)((const char*)(ctx_s[BUF]) + rb0);   \
            bf16x8 a1 = *(const bf16x8*)((const char*)(ctx_s[BUF]) + rb1);   \
            int kglob = (KC) * 128 + k0;                                     \
            bf16x8 bfr = *(const bf16x8*)(W1e + ((size_t)(kglob >> 3) * 64 + colw) * 8); \
            acc0 = __builtin_amdgcn_mfma_f32_16x16x32_bf16(a0, bfr, acc0, 0, 0, 0); \
            acc1 = __builtin_amdgcn_mfma_f32_16x16x32_bf16(a1, bfr, acc1, 0, 0, 0); \
        }                                                                    \
    } while (0)

    f32x4 acc0 = {0.f,0.f,0.f,0.f}, acc1 = {0.f,0.f,0.f,0.f};
    float4 A0, A1, B0, B1;

    // 2-deep pipelined K loop: raw barriers keep next chunk's loads in flight
    LOADC(0, A0, A1);
    for (int kc2 = 0; kc2 < 32; kc2 += 2) {
        LOADC(kc2 + 1, B0, B1);
        PACKW(A0, A1, 0);
        asm volatile("s_waitcnt lgkmcnt(0)" ::: "memory");
        __builtin_amdgcn_s_barrier();
        MFMAC(kc2, 0);
        LOADC((kc2 + 2) & 31, A0, A1);     // wraps to 0 on last iter (discarded)
        PACKW(B0, B1, 1);
        asm volatile("s_waitcnt lgkmcnt(0)" ::: "memory");
        __builtin_amdgcn_s_barrier();
        MFMAC(kc2 + 1, 1);
    }

    // relu + bias -> hid LDS (bf16, swizzled). acc row = lq*4+i, col = colw
    {
        float b1v = b1[myE * CH + colw];
        int colh = ((w >= 4) ? 64 : 0) + colw;
        #pragma unroll
        for (int i = 0; i < 4; i++) {
            int r0 = lq * 4 + i;
            float h0 = acc0[i] + b1v; h0 = h0 > 0.f ? h0 : 0.f;
            float h1 = acc1[i] + b1v; h1 = h1 > 0.f ? h1 : 0.f;
            int by0 = (r0 * 256 + colh * 2) ^ ((r0 & 7) << 4);
            int by1 = ((r0 + 16) * 256 + colh * 2) ^ ((r0 & 7) << 4);
            *(unsigned short*)((char*)hid_s + by0) = bf1(h0);
            *(unsigned short*)((char*)hid_s + by1) = bf1(h1);
        }
    }
    asm volatile("s_waitcnt lgkmcnt(0)" ::: "memory");
    __builtin_amdgcn_s_barrier();

    // ---- stage 2: wave w owns o-band [w*128, w*128+128); per-expert-slot loop
    const unsigned short* W2lo = W2p + (size_t)lo * (CH * 3 * OD);
    const unsigned short* W2hi = W2p + (size_t)hi * (CH * 3 * OD);
    const float* b2lo = b2 + (size_t)lo * 3072;
    const float* b2hi = b2 + (size_t)hi * 3072;

    int   tok_r[2][4];
    float twx[2][4], twy[2][4];
    #pragma unroll
    for (int rt = 0; rt < 2; rt++)
        #pragma unroll
        for (int i = 0; i < 4; i++) {
            int trow = rt * 16 + lq * 4 + i;
            tok_r[rt][i] = toks[trow];
            float2 t2 = tw[trow];
            twx[rt][i] = t2.x; twy[rt][i] = t2.y;
        }

    for (int ot8 = 0; ot8 < 8; ot8++) {
        int o = w * 128 + ot8 * 16 + l15;
        float xo[2][4], vo[2][4];
        #pragma unroll
        for (int rt = 0; rt < 2; rt++)
            #pragma unroll
            for (int i = 0; i < 4; i++) {
                size_t off = (size_t)tok_r[rt][i] * OD + o;
                xo[rt][i] = x[off];
                vo[rt][i] = v[off];
            }
        float muo = mu[o];
        float accVN[2][4] = {{0.f,0.f,0.f,0.f},{0.f,0.f,0.f,0.f}};
        float accGV[2][4] = {{0.f,0.f,0.f,0.f},{0.f,0.f,0.f,0.f}};

        #pragma unroll
        for (int s = 0; s < 2; s++) {
            const unsigned short* W2e = s ? W2hi : W2lo;
            const float* b2e = s ? b2hi : b2lo;
            f32x4 aA[2] = {{0.f,0.f,0.f,0.f},{0.f,0.f,0.f,0.f}};
            f32x4 aB[2] = {{0.f,0.f,0.f,0.f},{0.f,0.f,0.f,0.f}};
            f32x4 aG[2] = {{0.f,0.f,0.f,0.f},{0.f,0.f,0.f,0.f}};
            #pragma unroll
            for (int ks = 0; ks < 2; ks++) {
                bf16x8 af0, af1;
                {
                    int col = s * 64 + ks * 32 + lq * 8;
                    int by0 = ((l15     ) * 256 + col * 2) ^ ((l15 & 7) << 4);
                    int by1 = ((l15 + 16) * 256 + col * 2) ^ ((l15 & 7) << 4);
                    af0 = *(const bf16x8*)((const char*)hid_s + by0);
                    af1 = *(const bf16x8*)((const char*)hid_s + by1);
                }
                int kb = ks * 4 + lq;
                bf16x8 wA = *(const bf16x8*)(W2e + ((size_t)kb * 3072 + o) * 8);
                bf16x8 wB = *(const bf16x8*)(W2e + ((size_t)kb * 3072 + OD + o) * 8);
                bf16x8 wG = *(const bf16x8*)(W2e + ((size_t)kb * 3072 + 2 * OD + o) * 8);
                aA[0] = __builtin_amdgcn_mfma_f32_16x16x32_bf16(af0, wA, aA[0], 0, 0, 0);
                aA[1] = __builtin_amdgcn_mfma_f32_16x16x32_bf16(af1, wA, aA[1], 0, 0, 0);
                aB[0] = __builtin_amdgcn_mfma_f32_16x16x32_bf16(af0, wB, aB[0], 0, 0, 0);
                aB[1] = __builtin_amdgcn_mfma_f32_16x16x32_bf16(af1, wB, aB[1], 0, 0, 0);
                aG[0] = __builtin_amdgcn_mfma_f32_16x16x32_bf16(af0, wG, aG[0], 0, 0, 0);
                aG[1] = __builtin_amdgcn_mfma_f32_16x16x32_bf16(af1, wG, aG[1], 0, 0, 0);
            }
            float ba = b2e[o], bb = b2e[OD + o], bg = b2e[2 * OD + o];
            #pragma unroll
            for (int rt = 0; rt < 2; rt++) {
                #pragma unroll
                for (int i = 0; i < 4; i++) {
                    float za = aA[rt][i] + ba;
                    float zb = aB[rt][i] + bb;
                    float zg = aG[rt][i] + bg;
                    float alpha = fsigmoid(za);
                    float beta  = fsoftplus(zb);
                    float gate  = fsigmoid(zg);
                    float ws = s ? twy[rt][i] : twx[rt][i];
                    float vn_s = alpha * vo[rt][i] - beta * (xo[rt][i] - muo);
                    accVN[rt][i] += ws * vn_s;
                    accGV[rt][i] += ws * gate * vn_s;
                }
            }
        }
        #pragma unroll
        for (int rt = 0; rt < 2; rt++)
            #pragma unroll
            for (int i = 0; i < 4; i++) {
                int trow = rt * 16 + lq * 4 + i;
                if (trow < nt) {
                    size_t off = (size_t)tok_r[rt][i] * OD + o;
                    out[off]          = xo[rt][i] + 0.1f * accGV[rt][i];
                    out[OFF_VN + off] = accVN[rt][i];
                }
            }
    }
#undef LOADC
#undef PACKW
#undef MFMAC
}

extern "C" void kernel_launch(void* const* d_in, const int* in_sizes, int n_in,
                              void* d_out, int out_size, void* d_ws, size_t ws_size,
                              hipStream_t stream)
{
    (void)in_sizes; (void)n_in; (void)out_size; (void)ws_size;
    const float* h  = (const float*)d_in[0];
    const float* x  = (const float*)d_in[1];
    const float* v  = (const float*)d_in[2];
    const float* rw = (const float*)d_in[3];
    const float* rb = (const float*)d_in[4];
    const float* mu = (const float*)d_in[5];
    const float* W1 = (const float*)d_in[6];
    const float* b1 = (const float*)d_in[7];
    const float* W2 = (const float*)d_in[8];
    const float* b2 = (const float*)d_in[9];
    float* out = (float*)d_out;

    char* ws = (char*)d_ws;
    int*    pcnt  = (int*)(ws + WS_PCNT);
    int*    total = (int*)(ws + WS_TOTAL);
    int*    table = (int*)(ws + WS_TABLE);
    int*    plist = (int*)(ws + WS_PLIST);
    float2* pwts  = (float2*)(ws + WS_PWTS);
    unsigned short* W1p = (unsigned short*)(ws + WS_W1P);
    unsigned short* W2p = (unsigned short*)(ws + WS_W2P);

    hipMemsetAsync(pcnt, 0, 64 * sizeof(int), stream);

    convert_w1<<<1024, 256, 0, stream>>>(W1, W1p);
    convert_w2<<<768, 256, 0, stream>>>(W2, W2p);
    router_kernel<<<NTOK / 4, 256, 0, stream>>>(h, rw, rb, out, pcnt, plist, pwts);
    prefix_kernel<<<1, 64, 0, stream>>>(pcnt, table, total);
    moe_kernel<<<576, 512, 0, stream>>>(h, x, v, mu, b1, b2, W1p, W2p,
                                        pcnt, table, total, plist, pwts, out);
}